// Round 4
// baseline (640.639 us; speedup 1.0000x reference)
//
#include <hip/hip_runtime.h>

#define ALPHA 0.2f

typedef const __attribute__((address_space(1))) unsigned int gu32;
typedef __attribute__((address_space(3))) unsigned int lu32;

// Cross-block state in module-owned device globals (d_ws avoided).
// No atomics anywhere: every buffer is fully overwritten each launch
// before it is read, so no zero-init kernel is needed.
__device__ float g_part[8192 * 576];   // per-pos partials: E[64] | S[v][ch] (8*64)
__device__ float g_red[2 * 64 * 1024]; // stage-1 tree: [l|S][bc 64][i 1024]
__device__ float g_ctx[1024];          // ctx[n][ch][v]  (n*512 + ch*8 + v)

// =====================================================================
// Phase 1: block = (n, hw-pair): 2 spatial positions x 64 tokens.
// Wave w owns a UNIFORM 32-channel slice (w0,w1 = K 0-31/32-63;
// w2,w3 = V 0-31/32-63). W staged ONCE in LDS [d][128] via glds;
// inner loop reads it as wave-uniform broadcast ds_read_b128 (in-order
// DS -> fine-grained lgkmcnt pipelining; NO SMEM drains). x read per-d
// as coalesced f2 (512B/wave). W2 overlaid by eK/vV after the GEMM.
// pS plane-major [v][256] -> conflict-free LDS.
// =====================================================================
__global__ __launch_bounds__(256) void k_kv(
    const float* __restrict__ x,
    const float* __restrict__ Wk, const float* __restrict__ sk, const float* __restrict__ bk,
    const float* __restrict__ Wv, const float* __restrict__ sv, const float* __restrict__ bv)
{
  __shared__ __align__(16) float sh[11008];  // W2[64][128] -> eK[64][68]|vV[64][68]; pE[256]; pS[8][256]
  float* W2 = sh;            // [d][128] during GEMM (cols 0-63 K, 64-127 V)
  float* eK = sh;            // [64][68] after GEMM
  float* vV = sh + 4352;
  float* pE = sh + 8704;     // [4][64]
  float* pS = sh + 8960;     // [v][256] plane-major

  const int tid = threadIdx.x;
  const int bid = blockIdx.x;            // 0..4095
  const int n   = bid >> 11;
  const int hw0 = (bid & 2047) * 2;

  // stage W2 = [Wk | Wv]: dest byte offset = idx*16 -> linear per wave
  #pragma unroll
  for (int i = 0; i < 8; ++i) {
    int idx = tid + i * 256;              // float4 id 0..2047
    int d = idx >> 5, e4 = (idx & 31) * 4;
    const float* src = (e4 < 64) ? (Wk + d * 64 + e4) : (Wv + d * 64 + e4 - 64);
    __builtin_amdgcn_global_load_lds((gu32*)src, (lu32*)&W2[idx * 4], 16, 0, 0);
  }

  const int pr  = tid & 63;              // token pair: floats 2pr, 2pr+1
  const int wv  = tid >> 6;              // 0..3
  const bool isK = (wv < 2);
  const int cbase = 32 * (wv & 1);
  const int wcol  = wv * 32;             // slice in W2 columns
  const float* sp = (isK ? sk : sv) + cbase;
  const float* bp = (isK ? bk : bv) + cbase;

  // affine params (wave-uniform, one-time)
  float s8a[8][4], b8a[8][4];
  #pragma unroll
  for (int q = 0; q < 8; ++q) {
    *(float4*)&s8a[q][0] = *(const float4*)(sp + q * 4);
    *(float4*)&b8a[q][0] = *(const float4*)(bp + q * 4);
  }

  const float* xg = x + (size_t)n * 16777216u + (size_t)hw0 * 64u + 2 * pr;

  float acc[2][32];
  #pragma unroll
  for (int t = 0; t < 2; ++t)
    #pragma unroll
    for (int c = 0; c < 32; ++c) acc[t][c] = 0.f;

  __syncthreads();   // W2 staged (barrier drains vmcnt)

  #pragma unroll 2
  for (int d = 0; d < 64; ++d) {
    float2 xv = *(const float2*)(xg + (size_t)d * 262144u);
    const float* wrow = &W2[d * 128 + wcol];   // wave-uniform LDS addr -> broadcast
    #pragma unroll
    for (int q = 0; q < 8; ++q) {
      float4 w = *(const float4*)(wrow + q * 4);
      acc[0][q*4+0] += xv.x * w.x; acc[0][q*4+1] += xv.x * w.y;
      acc[0][q*4+2] += xv.x * w.z; acc[0][q*4+3] += xv.x * w.w;
      acc[1][q*4+0] += xv.y * w.x; acc[1][q*4+1] += xv.y * w.y;
      acc[1][q*4+2] += xv.y * w.z; acc[1][q*4+3] += xv.y * w.w;
    }
  }

  // affine + LReLU (+ exp-clamp on K side), in place
  #pragma unroll
  for (int q = 0; q < 8; ++q) {
    #pragma unroll
    for (int j = 0; j < 4; ++j) {
      #pragma unroll
      for (int t = 0; t < 2; ++t) {
        float y = acc[t][q*4+j] * s8a[q][j] + b8a[q][j];
        y = (y >= 0.f) ? y : ALPHA * y;
        if (isK) y = __expf(fminf(y, 60.f));
        acc[t][q*4+j] = y;
      }
    }
  }

  __syncthreads();   // all GEMM reads of W2 done -> overlay eK/vV

  const int prl = pr & 31;
  float* dstbuf = isK ? eK : vV;
  const int ch = tid & 63, tq = tid >> 6, a8 = ch & ~7;

  #pragma unroll
  for (int ph = 0; ph < 2; ++ph) {
    if ((pr >> 5) == ph) {               // this lane's position == ph
      #pragma unroll
      for (int t = 0; t < 2; ++t)
        #pragma unroll
        for (int q = 0; q < 8; ++q)
          *(float4*)&dstbuf[(prl*2 + t) * 68 + cbase + q*4] = *(float4*)&acc[t][q*4];
    }
    __syncthreads();

    float E = 0.f;
    float S[8];
    #pragma unroll
    for (int v = 0; v < 8; ++v) S[v] = 0.f;
    for (int t = tq * 16; t < tq * 16 + 16; ++t) {
      float e = eK[t * 68 + ch];
      float4 v0 = *(const float4*)&vV[t * 68 + a8];
      float4 v1 = *(const float4*)&vV[t * 68 + a8 + 4];
      E += e;
      S[0] += e * v0.x; S[1] += e * v0.y; S[2] += e * v0.z; S[3] += e * v0.w;
      S[4] += e * v1.x; S[5] += e * v1.y; S[6] += e * v1.z; S[7] += e * v1.w;
    }
    pE[tq * 64 + ch] = E;
    #pragma unroll
    for (int v = 0; v < 8; ++v) pS[v * 256 + tq * 64 + ch] = S[v];   // plane-major
    __syncthreads();

    if (tid < 64) {
      float* gp = g_part + ((size_t)bid * 2u + ph) * 576u;
      float E4 = pE[tid] + pE[64 + tid] + pE[128 + tid] + pE[192 + tid];
      gp[tid] = E4;
      #pragma unroll
      for (int v = 0; v < 8; ++v) {
        float S4 = pS[v * 256 + tid] + pS[v * 256 + 64 + tid]
                 + pS[v * 256 + 128 + tid] + pS[v * 256 + 192 + tid];
        gp[64 + v * 64 + tid] = S4;
      }
    }
  }
}

// =====================================================================
// Phase 1.25: stage-1 tree reduce (256 blocks: 64 chunks x 4 out-chunks).
// =====================================================================
__global__ __launch_bounds__(256) void k_red() {
  const int ob = blockIdx.x & 3;
  const int bc = blockIdx.x >> 2;                 // 0..63
  const int i  = ob * 256 + threadIdx.x;          // i = n*512 + ch*8 + v
  const int n = i >> 9, ch = (i & 511) >> 3, v = i & 7;
  const float* base = g_part + ((size_t)n * 4096u + (size_t)bc * 64u) * 576u;
  float l = 0.f, S = 0.f;
  #pragma unroll 8
  for (int b = 0; b < 64; ++b) {
    l += base[(size_t)b * 576u + ch];
    S += base[(size_t)b * 576u + 64u + (size_t)v * 64u + ch];
  }
  g_red[bc * 1024 + i]         = l;
  g_red[65536 + bc * 1024 + i] = S;
}

// =====================================================================
// Phase 1.5: final reduce -> guarded ctx (NaN structurally impossible).
// =====================================================================
__global__ __launch_bounds__(256) void k_ctx() {
  int i = blockIdx.x * 256 + threadIdx.x;   // i = n*512 + ch*8 + v
  if (i >= 1024) return;
  float l = 0.f, S = 0.f;
  #pragma unroll
  for (int r = 0; r < 64; ++r) {
    l += g_red[r * 1024 + i];
    S += g_red[65536 + r * 1024 + i];
  }
  float c = (l > 0.f) ? (S / l) : 0.f;
  if (!(__builtin_fabsf(c) < 1e30f)) c = 0.f;   // catches NaN/inf too
  g_ctx[i] = c;
}

// =====================================================================
// Phase 2: jc-swizzled blockIdx (x-gather line reuse across 8 blocks).
// Q-GEMM from LDS. agg f4 (qL rotation swizzle). rep GEMM: Wr staged
// via glds into xw (dead after Q-GEMM), read as wave-uniform broadcast
// ds_read_b128 (no SMEM drains). LDS 52.5KB -> 3 blocks/CU.
// =====================================================================
__global__ __launch_bounds__(256) void k_att(
    const float* __restrict__ x,
    const float* __restrict__ Wq, const float* __restrict__ sq, const float* __restrict__ bq,
    const float* __restrict__ Wr, const float* __restrict__ sr, const float* __restrict__ br,
    float* __restrict__ out)
{
  __shared__ __align__(16) float WqA[64 * 68];   // Wq [d][ch] (stride 64), then aggL [c'][e] stride 68
  __shared__ __align__(16) float xw[64 * 64];    // xql [d][tok], then WrL [e][d]
  __shared__ __align__(16) float qL[64 * 64];    // [tok][rot-swizzled ch]
  __shared__ __align__(16) float ctxL[64 * 12];  // [a*8+k][v] stride 12
  __shared__ float srL[64], brL[64];

  const int tid = threadIdx.x;
  const int lin = blockIdx.x;

  // jc-swizzle decode (bijective: lin = rest<<6 | jc<<3 | xcd)
  const int xcd   = lin & 7;
  const int jc    = (lin >> 3) & 7;
  const int rest  = lin >> 6;              // 0..127
  const int combo = rest * 8 + xcd;        // 0..1023 -> (n, hp_lo, wp)
  const int n     = combo >> 9;
  const int hp_lo = (combo >> 6) & 7;
  const int wp    = combo & 63;
  const int hp    = jc * 8 + hp_lo;
  const int hwp   = hp * 64 + wp;

  const int h_t   = hp_lo * 8 + (wp >> 3);
  const int wbase = (wp & 7) * 8;

  // stage Wq: dest byte offset = idx*16 -> linear per wave
  #pragma unroll
  for (int i = 0; i < 4; ++i) {
    int idx = tid + i * 256;
    __builtin_amdgcn_global_load_lds((gu32*)(Wq + idx * 4),
                                     (lu32*)&WqA[idx * 4], 16, 0, 0);
  }
  if (tid < 64) { srL[tid] = sr[tid]; brL[tid] = br[tid]; }

  for (int i = tid; i < 512; i += 256) {
    int ch = i >> 3, v = i & 7;
    ctxL[ch * 12 + v] = g_ctx[n * 512 + ch * 8 + v];
  }

  // gather x for the 64 needed tokens: xw[d][tok], tok = v''*8 + c'low
  {
    const size_t xb = (size_t)n * 16777216u + (size_t)h_t * 4096u;
    #pragma unroll
    for (int i = 0; i < 16; ++i) {
      int idx = tid + i * 256;
      int d = idx >> 6, tok = idx & 63;
      int vpp = tok >> 3, cl = tok & 7;
      xw[d * 64 + tok] = x[xb + (size_t)d * 262144u + (size_t)(wbase + vpp) * 64u + (cl * 8 + jc)];
    }
  }
  __syncthreads();

  // Q GEMM (2 tok x 8 ch per thread) + affine + LReLU + softmax over head
  {
    const int tok0 = (tid & 31) * 2;
    const int ch0  = (tid >> 5) * 8;
    float acc0[8], acc1[8];
    #pragma unroll
    for (int j = 0; j < 8; ++j) { acc0[j] = 0.f; acc1[j] = 0.f; }
    #pragma unroll 4
    for (int d = 0; d < 64; ++d) {
      float2 xv = *(const float2*)&xw[d * 64 + tok0];
      float4 wa = *(const float4*)&WqA[d * 64 + ch0];
      float4 wb = *(const float4*)&WqA[d * 64 + ch0 + 4];
      float w[8] = {wa.x, wa.y, wa.z, wa.w, wb.x, wb.y, wb.z, wb.w};
      #pragma unroll
      for (int j = 0; j < 8; ++j) { acc0[j] += xv.x * w[j]; acc1[j] += xv.y * w[j]; }
    }
    float sv8[8], bv8[8];
    *(float4*)&sv8[0] = *(const float4*)(sq + ch0);
    *(float4*)&sv8[4] = *(const float4*)(sq + ch0 + 4);
    *(float4*)&bv8[0] = *(const float4*)(bq + ch0);
    *(float4*)&bv8[4] = *(const float4*)(bq + ch0 + 4);
    #pragma unroll
    for (int i = 0; i < 2; ++i) {
      float* a = (i == 0) ? acc0 : acc1;
      float mx = -3.0e38f;
      #pragma unroll
      for (int j = 0; j < 8; ++j) {
        float y = a[j] * sv8[j] + bv8[j];
        y = (y >= 0.f) ? y : ALPHA * y;
        a[j] = y;
        mx = fmaxf(mx, y);
      }
      float sum = 0.f;
      #pragma unroll
      for (int j = 0; j < 8; ++j) { a[j] = __expf(a[j] - mx); sum += a[j]; }
      float inv = 1.f / sum;
      float o8[8];
      #pragma unroll
      for (int j = 0; j < 8; ++j) o8[j] = a[j] * inv;
      const int t = tok0 + i;
      const int rot = (4 * t) & 63;
      *(float4*)&qL[t * 64 + ((ch0 + rot) & 63)]     = *(float4*)&o8[0];
      *(float4*)&qL[t * 64 + ((ch0 + 4 + rot) & 63)] = *(float4*)&o8[4];
    }
  }
  __syncthreads();   // Q-GEMM done with xw & WqA -> repurpose both

  // stage Wr into xw: dest byte offset = idx*16 -> linear per wave
  #pragma unroll
  for (int i = 0; i < 4; ++i) {
    int idx = tid + i * 256;
    __builtin_amdgcn_global_load_lds((gu32*)(Wr + idx * 4),
                                     (lu32*)&xw[idx * 4], 16, 0, 0);
  }

  // agg[c'][e] into aggL (= WqA region, stride 68), f4 reads + f4 writes
  {
    float* aggL = WqA;
    const int cp = tid & 63, eb = tid >> 6;
    const int kk = cp >> 3, cl = cp & 7;
    #pragma unroll
    for (int j4 = 0; j4 < 4; ++j4) {
      float s4[4];
      #pragma unroll
      for (int jj = 0; jj < 4; ++jj) {
        int e = eb * 16 + j4 * 4 + jj;
        int a = e >> 3, vpp = e & 7;
        float4 c0 = *(const float4*)&ctxL[(a * 8 + kk) * 12];
        float4 c1 = *(const float4*)&ctxL[(a * 8 + kk) * 12 + 4];
        int t = vpp * 8 + cl;
        int rot = (4 * t) & 63;
        float4 q0 = *(const float4*)&qL[t * 64 + ((a * 8 + rot) & 63)];
        float4 q1 = *(const float4*)&qL[t * 64 + ((a * 8 + 4 + rot) & 63)];
        s4[jj] = q0.x * c0.x + q0.y * c0.y + q0.z * c0.z + q0.w * c0.w
               + q1.x * c1.x + q1.y * c1.y + q1.z * c1.z + q1.w * c1.w;
      }
      *(float4*)&aggL[cp * 68 + eb * 16 + j4 * 4] =
          make_float4(s4[0], s4[1], s4[2], s4[3]);
    }
  }
  __syncthreads();   // drains Wr vmcnt too

  // rep GEMM + residual. Wr rows from LDS as wave-uniform broadcast b128.
  {
    const float* aggL = WqA;
    const int ci = tid & 63, dq = tid >> 6;
    float accr[16];
    #pragma unroll
    for (int i = 0; i < 16; ++i) accr[i] = 0.f;
    #pragma unroll 4
    for (int ec = 0; ec < 16; ++ec) {
      float4 a4 = *(const float4*)&aggL[ci * 68 + ec * 4];
      float av[4] = {a4.x, a4.y, a4.z, a4.w};
      #pragma unroll
      for (int j = 0; j < 4; ++j) {
        const float* wrow = &xw[(ec * 4 + j) * 64 + dq * 16];   // wave-uniform -> broadcast
        float4 w0 = *(const float4*)(wrow);
        float4 w1 = *(const float4*)(wrow + 4);
        float4 w2 = *(const float4*)(wrow + 8);
        float4 w3 = *(const float4*)(wrow + 12);
        float aj = av[j];
        accr[0]  += aj * w0.x; accr[1]  += aj * w0.y; accr[2]  += aj * w0.z; accr[3]  += aj * w0.w;
        accr[4]  += aj * w1.x; accr[5]  += aj * w1.y; accr[6]  += aj * w1.z; accr[7]  += aj * w1.w;
        accr[8]  += aj * w2.x; accr[9]  += aj * w2.y; accr[10] += aj * w2.z; accr[11] += aj * w2.w;
        accr[12] += aj * w3.x; accr[13] += aj * w3.y; accr[14] += aj * w3.z; accr[15] += aj * w3.w;
      }
    }
    const size_t xb = (size_t)n * 16777216u + (size_t)hwp * 64u + (size_t)ci;
    #pragma unroll
    for (int i = 0; i < 16; ++i) {
      int di = dq * 16 + i;
      float y = accr[i] * srL[di] + brL[di];
      y = (y >= 0.f) ? y : ALPHA * y;
      out[xb + (size_t)di * 262144u] = x[xb + (size_t)di * 262144u] + y;
    }
  }
}

// =====================================================================
extern "C" void kernel_launch(void* const* d_in, const int* in_sizes, int n_in,
                              void* d_out, int out_size, void* d_ws, size_t ws_size,
                              hipStream_t stream)
{
  (void)in_sizes; (void)n_in; (void)out_size; (void)d_ws; (void)ws_size;

  const float* x  = (const float*)d_in[0];
  const float* Wk = (const float*)d_in[1];
  const float* sk = (const float*)d_in[2];
  const float* bk = (const float*)d_in[3];
  const float* Wq = (const float*)d_in[4];
  const float* sq = (const float*)d_in[5];
  const float* bq = (const float*)d_in[6];
  const float* Wv = (const float*)d_in[7];
  const float* sv = (const float*)d_in[8];
  const float* bv = (const float*)d_in[9];
  const float* Wr = (const float*)d_in[10];
  const float* sr = (const float*)d_in[11];
  const float* br = (const float*)d_in[12];
  float* out = (float*)d_out;

  k_kv  <<<dim3(4096), dim3(256), 0, stream>>>(x, Wk, sk, bk, Wv, sv, bv);
  k_red <<<dim3(256),  dim3(256), 0, stream>>>();
  k_ctx <<<dim3(4),    dim3(256), 0, stream>>>();
  k_att <<<dim3(8192), dim3(256), 0, stream>>>(x, Wq, sq, bq, Wr, sr, br, out);
}

// Round 5
// 509.772 us; speedup vs baseline: 1.2567x; 1.2567x over previous
//
#include <hip/hip_runtime.h>

#define ALPHA 0.2f

typedef const __attribute__((address_space(1))) unsigned int gu32;
typedef __attribute__((address_space(3))) unsigned int lu32;

// Cross-block state in module-owned device globals (d_ws avoided).
// No atomics anywhere: every buffer is fully overwritten each launch
// before it is read, so no zero-init kernel is needed.
__device__ float g_part[8192 * 576];   // per-pos partials: E[64] | S[v][ch] (8*64)
__device__ float g_red[2 * 64 * 1024]; // stage-1 tree: [l|S][bc 64][i 1024]
__device__ float g_ctx[1024];          // ctx[n][ch][v]  (n*512 + ch*8 + v)

// =====================================================================
// Phase 1: block = (n, hw-quad): 4 spatial positions x 64 tokens.
// Wave w owns a UNIFORM 32-channel slice (w0,w1 = K 0-31/32-63;
// w2,w3 = V 0-31/32-63): W read via wave-uniform pointers -> s_load
// (scalar cache resident, ZERO DS traffic in the GEMM -- the DS pipe
// is per-CU shared and broadcast ds_reads poisoned r4). x read per-d
// as one coalesced f4 per lane (1KB/wave). 4 positions per block
// halves W-load traffic per FMA vs r3 and doubles FMA-per-load for
// latency hiding. Affine s/b stay in SGPRs (uniform), applied
// post-GEMM. Epilogue: 4 sequential phases on shared eK/vV buffers.
// =====================================================================
__global__ __launch_bounds__(256, 3) void k_kv(
    const float* __restrict__ x,
    const float* __restrict__ Wk, const float* __restrict__ sk, const float* __restrict__ bk,
    const float* __restrict__ Wv, const float* __restrict__ sv, const float* __restrict__ bv)
{
  __shared__ __align__(16) float sh[11008];  // eK[64][68] | vV[64][68] | pE[256] | pS[8][256]
  float* eK = sh;            // [64][68]
  float* vV = sh + 4352;     // [64][68]
  float* pE = sh + 8704;     // [4][64]
  float* pS = sh + 8960;     // [v][256] plane-major

  const int tid = threadIdx.x;
  const int bid = blockIdx.x;            // 0..2047
  const int n   = bid >> 10;
  const int hw0 = (bid & 1023) * 4;

  const int pr  = tid & 63;              // token quad: floats 4pr .. 4pr+3
  const int wv  = __builtin_amdgcn_readfirstlane(tid >> 6);
  const bool isK = (wv < 2);
  const int cbase = 32 * (wv & 1);
  const float* Wsrc = (isK ? Wk : Wv) + cbase;
  const float* sp   = (isK ? sk : sv) + cbase;
  const float* bp   = (isK ? bk : bv) + cbase;

  const float* xg = x + (size_t)n * 16777216u + (size_t)hw0 * 64u + 4 * pr;

  float acc[4][32];
  #pragma unroll
  for (int t = 0; t < 4; ++t)
    #pragma unroll
    for (int c = 0; c < 32; ++c) acc[t][c] = 0.f;

  #pragma unroll 2
  for (int d = 0; d < 64; ++d) {
    float4 xv = *(const float4*)(xg + (size_t)d * 262144u);
    const float* wrow = Wsrc + d * 64;   // wave-uniform address -> s_load
    #pragma unroll
    for (int q = 0; q < 8; ++q) {
      float4 w = *(const float4*)(wrow + q * 4);
      acc[0][q*4+0] += xv.x * w.x; acc[0][q*4+1] += xv.x * w.y;
      acc[0][q*4+2] += xv.x * w.z; acc[0][q*4+3] += xv.x * w.w;
      acc[1][q*4+0] += xv.y * w.x; acc[1][q*4+1] += xv.y * w.y;
      acc[1][q*4+2] += xv.y * w.z; acc[1][q*4+3] += xv.y * w.w;
      acc[2][q*4+0] += xv.z * w.x; acc[2][q*4+1] += xv.z * w.y;
      acc[2][q*4+2] += xv.z * w.z; acc[2][q*4+3] += xv.z * w.w;
      acc[3][q*4+0] += xv.w * w.x; acc[3][q*4+1] += xv.w * w.y;
      acc[3][q*4+2] += xv.w * w.z; acc[3][q*4+3] += xv.w * w.w;
    }
  }

  // affine + LReLU (+ exp-clamp on K side), in place.
  // s/b via wave-uniform pointers -> SGPRs (no VGPR pressure).
  #pragma unroll
  for (int q = 0; q < 8; ++q) {
    float4 s4 = *(const float4*)(sp + q * 4);
    float4 b4 = *(const float4*)(bp + q * 4);
    float ss[4] = {s4.x, s4.y, s4.z, s4.w};
    float bb[4] = {b4.x, b4.y, b4.z, b4.w};
    #pragma unroll
    for (int j = 0; j < 4; ++j) {
      #pragma unroll
      for (int t = 0; t < 4; ++t) {
        float y = acc[t][q*4+j] * ss[j] + bb[j];
        y = (y >= 0.f) ? y : ALPHA * y;
        if (isK) y = __expf(fminf(y, 60.f));
        acc[t][q*4+j] = y;
      }
    }
  }

  const int prl = pr & 15;               // lane within its position group
  float* dstbuf = isK ? eK : vV;
  const int ch = tid & 63, tq = tid >> 6, a8 = ch & ~7;

  #pragma unroll
  for (int ph = 0; ph < 4; ++ph) {
    if ((pr >> 4) == ph) {               // this lane's position == ph
      #pragma unroll
      for (int t = 0; t < 4; ++t)
        #pragma unroll
        for (int q = 0; q < 8; ++q)
          *(float4*)&dstbuf[(prl*4 + t) * 68 + cbase + q*4] = *(float4*)&acc[t][q*4];
    }
    __syncthreads();

    float E = 0.f;
    float S[8];
    #pragma unroll
    for (int v = 0; v < 8; ++v) S[v] = 0.f;
    for (int t = tq * 16; t < tq * 16 + 16; ++t) {
      float e = eK[t * 68 + ch];
      float4 v0 = *(const float4*)&vV[t * 68 + a8];
      float4 v1 = *(const float4*)&vV[t * 68 + a8 + 4];
      E += e;
      S[0] += e * v0.x; S[1] += e * v0.y; S[2] += e * v0.z; S[3] += e * v0.w;
      S[4] += e * v1.x; S[5] += e * v1.y; S[6] += e * v1.z; S[7] += e * v1.w;
    }
    pE[tq * 64 + ch] = E;
    #pragma unroll
    for (int v = 0; v < 8; ++v) pS[v * 256 + tq * 64 + ch] = S[v];   // plane-major
    __syncthreads();

    if (tid < 64) {
      float* gp = g_part + ((size_t)bid * 4u + ph) * 576u;
      float E4 = pE[tid] + pE[64 + tid] + pE[128 + tid] + pE[192 + tid];
      gp[tid] = E4;
      #pragma unroll
      for (int v = 0; v < 8; ++v) {
        float S4 = pS[v * 256 + tid] + pS[v * 256 + 64 + tid]
                 + pS[v * 256 + 128 + tid] + pS[v * 256 + 192 + tid];
        gp[64 + v * 64 + tid] = S4;
      }
    }
  }
}

// =====================================================================
// Phase 1.25: stage-1 tree reduce (256 blocks: 64 chunks x 4 out-chunks).
// =====================================================================
__global__ __launch_bounds__(256) void k_red() {
  const int ob = blockIdx.x & 3;
  const int bc = blockIdx.x >> 2;                 // 0..63
  const int i  = ob * 256 + threadIdx.x;          // i = n*512 + ch*8 + v
  const int n = i >> 9, ch = (i & 511) >> 3, v = i & 7;
  const float* base = g_part + ((size_t)n * 4096u + (size_t)bc * 64u) * 576u;
  float l = 0.f, S = 0.f;
  #pragma unroll 8
  for (int b = 0; b < 64; ++b) {
    l += base[(size_t)b * 576u + ch];
    S += base[(size_t)b * 576u + 64u + (size_t)v * 64u + ch];
  }
  g_red[bc * 1024 + i]         = l;
  g_red[65536 + bc * 1024 + i] = S;
}

// =====================================================================
// Phase 1.5: final reduce -> guarded ctx (NaN structurally impossible).
// =====================================================================
__global__ __launch_bounds__(256) void k_ctx() {
  int i = blockIdx.x * 256 + threadIdx.x;   // i = n*512 + ch*8 + v
  if (i >= 1024) return;
  float l = 0.f, S = 0.f;
  #pragma unroll
  for (int r = 0; r < 64; ++r) {
    l += g_red[r * 1024 + i];
    S += g_red[65536 + r * 1024 + i];
  }
  float c = (l > 0.f) ? (S / l) : 0.f;
  if (!(__builtin_fabsf(c) < 1e30f)) c = 0.f;   // catches NaN/inf too
  g_ctx[i] = c;
}

// =====================================================================
// Phase 2: unchanged from round 4 (measured ~195 us; one-variable round).
// jc-swizzled blockIdx (x-gather line reuse across 8 blocks). Q-GEMM
// from LDS; agg f4 (qL rotation swizzle); rep GEMM from staged Wr.
// =====================================================================
__global__ __launch_bounds__(256) void k_att(
    const float* __restrict__ x,
    const float* __restrict__ Wq, const float* __restrict__ sq, const float* __restrict__ bq,
    const float* __restrict__ Wr, const float* __restrict__ sr, const float* __restrict__ br,
    float* __restrict__ out)
{
  __shared__ __align__(16) float WqA[64 * 68];   // Wq [d][ch] (stride 64), then aggL [c'][e] stride 68
  __shared__ __align__(16) float xw[64 * 64];    // xql [d][tok], then WrL [e][d]
  __shared__ __align__(16) float qL[64 * 64];    // [tok][rot-swizzled ch]
  __shared__ __align__(16) float ctxL[64 * 12];  // [a*8+k][v] stride 12
  __shared__ float srL[64], brL[64];

  const int tid = threadIdx.x;
  const int lin = blockIdx.x;

  // jc-swizzle decode (bijective: lin = rest<<6 | jc<<3 | xcd)
  const int xcd   = lin & 7;
  const int jc    = (lin >> 3) & 7;
  const int rest  = lin >> 6;              // 0..127
  const int combo = rest * 8 + xcd;        // 0..1023 -> (n, hp_lo, wp)
  const int n     = combo >> 9;
  const int hp_lo = (combo >> 6) & 7;
  const int wp    = combo & 63;
  const int hp    = jc * 8 + hp_lo;
  const int hwp   = hp * 64 + wp;

  const int h_t   = hp_lo * 8 + (wp >> 3);
  const int wbase = (wp & 7) * 8;

  // stage Wq: dest byte offset = idx*16 -> linear per wave
  #pragma unroll
  for (int i = 0; i < 4; ++i) {
    int idx = tid + i * 256;
    __builtin_amdgcn_global_load_lds((gu32*)(Wq + idx * 4),
                                     (lu32*)&WqA[idx * 4], 16, 0, 0);
  }
  if (tid < 64) { srL[tid] = sr[tid]; brL[tid] = br[tid]; }

  for (int i = tid; i < 512; i += 256) {
    int ch = i >> 3, v = i & 7;
    ctxL[ch * 12 + v] = g_ctx[n * 512 + ch * 8 + v];
  }

  // gather x for the 64 needed tokens: xw[d][tok], tok = v''*8 + c'low
  {
    const size_t xb = (size_t)n * 16777216u + (size_t)h_t * 4096u;
    #pragma unroll
    for (int i = 0; i < 16; ++i) {
      int idx = tid + i * 256;
      int d = idx >> 6, tok = idx & 63;
      int vpp = tok >> 3, cl = tok & 7;
      xw[d * 64 + tok] = x[xb + (size_t)d * 262144u + (size_t)(wbase + vpp) * 64u + (cl * 8 + jc)];
    }
  }
  __syncthreads();

  // Q GEMM (2 tok x 8 ch per thread) + affine + LReLU + softmax over head
  {
    const int tok0 = (tid & 31) * 2;
    const int ch0  = (tid >> 5) * 8;
    float acc0[8], acc1[8];
    #pragma unroll
    for (int j = 0; j < 8; ++j) { acc0[j] = 0.f; acc1[j] = 0.f; }
    #pragma unroll 4
    for (int d = 0; d < 64; ++d) {
      float2 xv = *(const float2*)&xw[d * 64 + tok0];
      float4 wa = *(const float4*)&WqA[d * 64 + ch0];
      float4 wb = *(const float4*)&WqA[d * 64 + ch0 + 4];
      float w[8] = {wa.x, wa.y, wa.z, wa.w, wb.x, wb.y, wb.z, wb.w};
      #pragma unroll
      for (int j = 0; j < 8; ++j) { acc0[j] += xv.x * w[j]; acc1[j] += xv.y * w[j]; }
    }
    float sv8[8], bv8[8];
    *(float4*)&sv8[0] = *(const float4*)(sq + ch0);
    *(float4*)&sv8[4] = *(const float4*)(sq + ch0 + 4);
    *(float4*)&bv8[0] = *(const float4*)(bq + ch0);
    *(float4*)&bv8[4] = *(const float4*)(bq + ch0 + 4);
    #pragma unroll
    for (int i = 0; i < 2; ++i) {
      float* a = (i == 0) ? acc0 : acc1;
      float mx = -3.0e38f;
      #pragma unroll
      for (int j = 0; j < 8; ++j) {
        float y = a[j] * sv8[j] + bv8[j];
        y = (y >= 0.f) ? y : ALPHA * y;
        a[j] = y;
        mx = fmaxf(mx, y);
      }
      float sum = 0.f;
      #pragma unroll
      for (int j = 0; j < 8; ++j) { a[j] = __expf(a[j] - mx); sum += a[j]; }
      float inv = 1.f / sum;
      float o8[8];
      #pragma unroll
      for (int j = 0; j < 8; ++j) o8[j] = a[j] * inv;
      const int t = tok0 + i;
      const int rot = (4 * t) & 63;
      *(float4*)&qL[t * 64 + ((ch0 + rot) & 63)]     = *(float4*)&o8[0];
      *(float4*)&qL[t * 64 + ((ch0 + 4 + rot) & 63)] = *(float4*)&o8[4];
    }
  }
  __syncthreads();   // Q-GEMM done with xw & WqA -> repurpose both

  // stage Wr into xw: dest byte offset = idx*16 -> linear per wave
  #pragma unroll
  for (int i = 0; i < 4; ++i) {
    int idx = tid + i * 256;
    __builtin_amdgcn_global_load_lds((gu32*)(Wr + idx * 4),
                                     (lu32*)&xw[idx * 4], 16, 0, 0);
  }

  // agg[c'][e] into aggL (= WqA region, stride 68), f4 reads + f4 writes
  {
    float* aggL = WqA;
    const int cp = tid & 63, eb = tid >> 6;
    const int kk = cp >> 3, cl = cp & 7;
    #pragma unroll
    for (int j4 = 0; j4 < 4; ++j4) {
      float s4[4];
      #pragma unroll
      for (int jj = 0; jj < 4; ++jj) {
        int e = eb * 16 + j4 * 4 + jj;
        int a = e >> 3, vpp = e & 7;
        float4 c0 = *(const float4*)&ctxL[(a * 8 + kk) * 12];
        float4 c1 = *(const float4*)&ctxL[(a * 8 + kk) * 12 + 4];
        int t = vpp * 8 + cl;
        int rot = (4 * t) & 63;
        float4 q0 = *(const float4*)&qL[t * 64 + ((a * 8 + rot) & 63)];
        float4 q1 = *(const float4*)&qL[t * 64 + ((a * 8 + 4 + rot) & 63)];
        s4[jj] = q0.x * c0.x + q0.y * c0.y + q0.z * c0.z + q0.w * c0.w
               + q1.x * c1.x + q1.y * c1.y + q1.z * c1.z + q1.w * c1.w;
      }
      *(float4*)&aggL[cp * 68 + eb * 16 + j4 * 4] =
          make_float4(s4[0], s4[1], s4[2], s4[3]);
    }
  }
  __syncthreads();   // drains Wr vmcnt too

  // rep GEMM + residual. Wr rows from LDS (wave-uniform broadcast).
  {
    const float* aggL = WqA;
    const int ci = tid & 63, dq = tid >> 6;
    float accr[16];
    #pragma unroll
    for (int i = 0; i < 16; ++i) accr[i] = 0.f;
    #pragma unroll 4
    for (int ec = 0; ec < 16; ++ec) {
      float4 a4 = *(const float4*)&aggL[ci * 68 + ec * 4];
      float av[4] = {a4.x, a4.y, a4.z, a4.w};
      #pragma unroll
      for (int j = 0; j < 4; ++j) {
        const float* wrow = &xw[(ec * 4 + j) * 64 + dq * 16];   // wave-uniform -> broadcast
        float4 w0 = *(const float4*)(wrow);
        float4 w1 = *(const float4*)(wrow + 4);
        float4 w2 = *(const float4*)(wrow + 8);
        float4 w3 = *(const float4*)(wrow + 12);
        float aj = av[j];
        accr[0]  += aj * w0.x; accr[1]  += aj * w0.y; accr[2]  += aj * w0.z; accr[3]  += aj * w0.w;
        accr[4]  += aj * w1.x; accr[5]  += aj * w1.y; accr[6]  += aj * w1.z; accr[7]  += aj * w1.w;
        accr[8]  += aj * w2.x; accr[9]  += aj * w2.y; accr[10] += aj * w2.z; accr[11] += aj * w2.w;
        accr[12] += aj * w3.x; accr[13] += aj * w3.y; accr[14] += aj * w3.z; accr[15] += aj * w3.w;
      }
    }
    const size_t xb = (size_t)n * 16777216u + (size_t)hwp * 64u + (size_t)ci;
    #pragma unroll
    for (int i = 0; i < 16; ++i) {
      int di = dq * 16 + i;
      float y = accr[i] * srL[di] + brL[di];
      y = (y >= 0.f) ? y : ALPHA * y;
      out[xb + (size_t)di * 262144u] = x[xb + (size_t)di * 262144u] + y;
    }
  }
}

// =====================================================================
extern "C" void kernel_launch(void* const* d_in, const int* in_sizes, int n_in,
                              void* d_out, int out_size, void* d_ws, size_t ws_size,
                              hipStream_t stream)
{
  (void)in_sizes; (void)n_in; (void)out_size; (void)d_ws; (void)ws_size;

  const float* x  = (const float*)d_in[0];
  const float* Wk = (const float*)d_in[1];
  const float* sk = (const float*)d_in[2];
  const float* bk = (const float*)d_in[3];
  const float* Wq = (const float*)d_in[4];
  const float* sq = (const float*)d_in[5];
  const float* bq = (const float*)d_in[6];
  const float* Wv = (const float*)d_in[7];
  const float* sv = (const float*)d_in[8];
  const float* bv = (const float*)d_in[9];
  const float* Wr = (const float*)d_in[10];
  const float* sr = (const float*)d_in[11];
  const float* br = (const float*)d_in[12];
  float* out = (float*)d_out;

  k_kv  <<<dim3(2048), dim3(256), 0, stream>>>(x, Wk, sk, bk, Wv, sv, bv);
  k_red <<<dim3(256),  dim3(256), 0, stream>>>();
  k_ctx <<<dim3(4),    dim3(256), 0, stream>>>();
  k_att <<<dim3(8192), dim3(256), 0, stream>>>(x, Wq, sq, bq, Wr, sr, br, out);
}